// Round 5
// baseline (242.427 us; speedup 1.0000x reference)
//
#include <hip/hip_runtime.h>

#define M1      33                  // LPC_ORDER + 1
#define TROWS   64                  // rows per tile (= one wave, 1 row/thread)
#define BLK     64                  // single wave per block: no __syncthreads anywhere
#define TILE_F  (TROWS * M1)        // 2112 floats = 8448 B per tile
#define NLD     8                   // full-wave 16B global_load_lds per tile (+1 partial)
#define NST     8                   // full-wave 16B stores per tile (+1 partial)
#define PARTIAL 16                  // active lanes in the partial op (528 float4 = 8*64 + 16)
#define GRID    2304                // 9 blocks/CU * 256 CU (LDS 16.9 KB -> 9 resident)

typedef const __attribute__((address_space(1))) float* gptr_t;
typedef __attribute__((address_space(3))) float*       lptr_t;
// clang-native vector: __builtin_nontemporal_store rejects HIP_vector_type
typedef float nt_f4 __attribute__((ext_vector_type(4)));

// Stage one 8448 B tile global -> LDS, linear layout (wave-uniform base + lane*16).
// 9 vmcnt increments per call (8 full + 1 exec-masked, 16 lanes active).
// Loads stay CACHED (aux=0): the input is what we want L3 to retain.
__device__ __forceinline__ void stage_tile(const float* __restrict__ g,
                                           float* lds_base, int lane) {
    #pragma unroll
    for (int i = 0; i < NLD; ++i)
        __builtin_amdgcn_global_load_lds((gptr_t)(g + i * 256 + lane * 4),
                                         (lptr_t)(lds_base + i * 256), 16, 0, 0);
    if (lane < PARTIAL)
        __builtin_amdgcn_global_load_lds((gptr_t)(g + NLD * 256 + lane * 4),
                                         (lptr_t)(lds_base + NLD * 256), 16, 0, 0);
}

// Persistent single-wave blocks, double-buffered LDS, counted-vmcnt pipeline
// (identical to round 2 -- clean A/B). ONE delta: output stores are
// NON-TEMPORAL. Mechanism: cached stores write-allocate in L2/L3, and the
// 135 MB output stream evicts the 138 MB read-only input between bench
// iterations (input+output = 273 MB > 256 MB L3) -> FETCH_SIZE showed half
// the input re-fetched from HBM every run. nt stores stream past the caches,
// L3 retains the input, HBM does near-pure sequential writes (the regime
// where fillBufferAligned measures 6.7 TB/s on this same chip).
__global__ __launch_bounds__(BLK)
void parcor_to_lpc_kernel(const float* __restrict__ k, float* __restrict__ out,
                          int ntiles) {
    __shared__ __align__(16) float lds[2 * TILE_F];   // 16.9 KB -> 9 blocks/CU
    const int lane = threadIdx.x;

    int tile = blockIdx.x;
    if (tile >= ntiles) return;
    const int stride = gridDim.x;

    stage_tile(k + (size_t)tile * TILE_F, &lds[0], lane);

    int buf = 0;
    bool first = true;
    while (true) {
        const int next = tile + stride;

        // Wait for current tile's 9 loads (oldest outstanding). Steady state
        // leaves the previous tiles' 9 stores in flight.
        if (first) { asm volatile("s_waitcnt vmcnt(0)" ::: "memory"); first = false; }
        else       { asm volatile("s_waitcnt vmcnt(9)" ::: "memory"); }

        // Prefetch next tile into the other buffer; overlaps all of compute+store.
        if (next < ntiles)
            stage_tile(k + (size_t)next * TILE_F, &lds[(buf ^ 1) * TILE_F], lane);

        float* L = &lds[buf * TILE_F];

        // LDS -> registers: row stride 33 => bank (lane+j)%32, 2-way alias = free.
        float a[M1];
        #pragma unroll
        for (int j = 0; j < M1; ++j) a[j] = L[lane * M1 + j];

        // Levinson step-up recursion, fully unrolled, in registers.
        #pragma unroll
        for (int m = 2; m < M1; ++m) {
            const float km = a[m];
            #pragma unroll
            for (int j = 1; 2 * j < m; ++j) {
                const float x = a[j];
                const float y = a[m - j];
                a[j]     = fmaf(km, y, x);
                a[m - j] = fmaf(km, x, y);
            }
            if ((m & 1) == 0) {
                const int j = m >> 1;
                a[j] = fmaf(km, a[j], a[j]);   // midpoint: a[j]*(1+km)
            }
        }

        // registers -> LDS (own row), then cross-lane coalesced store.
        #pragma unroll
        for (int j = 0; j < M1; ++j) L[lane * M1 + j] = a[j];

        // Single wave: lgkmcnt(0) makes all 64 lanes' ds_writes visible to the
        // cross-lane b128 reads below (no s_barrier => no vmcnt(0) drain).
        asm volatile("s_waitcnt lgkmcnt(0)" ::: "memory");

        const nt_f4* l4 = (const nt_f4*)L;
        nt_f4* g4 = (nt_f4*)(out + (size_t)tile * TILE_F);
        #pragma unroll
        for (int i = 0; i < NST; ++i)
            __builtin_nontemporal_store(l4[i * BLK + lane], &g4[i * BLK + lane]);
        if (lane < PARTIAL)
            __builtin_nontemporal_store(l4[NST * BLK + lane], &g4[NST * BLK + lane]);

        if (next >= ntiles) break;
        tile = next;
        buf ^= 1;
    }
}

// Fallback for trailing rows (nrows % 64 != 0) -- not hit for 16x65536.
__global__ void parcor_to_lpc_tail_kernel(const float* __restrict__ k,
                                          float* __restrict__ out,
                                          int row_start, int nrows) {
    const int row = row_start + blockIdx.x * blockDim.x + threadIdx.x;
    if (row >= nrows) return;
    const float* src = k + (size_t)row * M1;
    float* dst = out + (size_t)row * M1;
    float a[M1];
    #pragma unroll
    for (int j = 0; j < M1; ++j) a[j] = src[j];
    #pragma unroll
    for (int m = 2; m < M1; ++m) {
        const float km = a[m];
        #pragma unroll
        for (int j = 1; 2 * j < m; ++j) {
            const float x = a[j];
            const float y = a[m - j];
            a[j]     = fmaf(km, y, x);
            a[m - j] = fmaf(km, x, y);
        }
        if ((m & 1) == 0) {
            const int j = m >> 1;
            a[j] = fmaf(km, a[j], a[j]);
        }
    }
    #pragma unroll
    for (int j = 0; j < M1; ++j) dst[j] = a[j];
}

extern "C" void kernel_launch(void* const* d_in, const int* in_sizes, int n_in,
                              void* d_out, int out_size, void* d_ws, size_t ws_size,
                              hipStream_t stream) {
    const float* k = (const float*)d_in[0];
    float* out = (float*)d_out;

    const int nrows     = in_sizes[0] / M1;    // 16 * 65536 = 1,048,576
    const int ntiles    = nrows / TROWS;       // 16384 tiles
    const int tile_rows = ntiles * TROWS;
    const int rem       = nrows - tile_rows;

    if (ntiles > 0) {
        const int grid = ntiles < GRID ? ntiles : GRID;
        parcor_to_lpc_kernel<<<grid, BLK, 0, stream>>>(k, out, ntiles);
    }
    if (rem > 0)
        parcor_to_lpc_tail_kernel<<<(rem + 63) / 64, 64, 0, stream>>>(
            k, out, tile_rows, nrows);
}